// Round 1
// baseline (235.609 us; speedup 1.0000x reference)
//
#include <hip/hip_runtime.h>
#include <math.h>

#define Bq 128
#define Nn 8
#define LQ 32
#define LD 256
#define DD 128
#define EPSN 1e-12f
#define NEGV (-9999.0f)

// ---------------- Kernel 1: normalize q rows over D ----------------
__global__ __launch_bounds__(256) void qnorm_k(const float* __restrict__ q,
                                               float* __restrict__ qn) {
    int row  = blockIdx.x * 4 + (threadIdx.x >> 6);   // 4096 rows total
    int lane = threadIdx.x & 63;
    size_t base = (size_t)row * DD + lane * 2;
    float2 v = *reinterpret_cast<const float2*>(q + base);
    float ss = v.x * v.x + v.y * v.y;
#pragma unroll
    for (int o = 32; o; o >>= 1) ss += __shfl_xor(ss, o);
    float inv = 1.0f / fmaxf(sqrtf(ss), EPSN);
    float2 o2; o2.x = v.x * inv; o2.y = v.y * inv;
    *reinterpret_cast<float2*>(qn + base) = o2;
}

// ---------------- Kernel 2: MaxSim scores ----------------
// grid = 2 * Nn * Bq blocks; block handles one (tensor, n, b).
// Thread t owns d-row t (256 rows). Streams the row through registers in
// 128B chunks; q read via wave-uniform (scalar) loads.
__global__ __launch_bounds__(256) void maxsim_k(const float* __restrict__ d_cq,
                                                const float* __restrict__ d_orig,
                                                const int* __restrict__ mask,
                                                const float* __restrict__ qn,
                                                float* __restrict__ scores) {
    int bid    = blockIdx.x;
    int tensor = bid >> 10;            // 0 = cq (student), 1 = orig (teacher)
    int nb     = bid & 1023;           // n*Bq + b
    int b      = nb & 127;

    const float* dbase = (tensor ? d_orig : d_cq) + (size_t)nb * LD * DD;
    int tid = threadIdx.x;
    const float* drow = dbase + (size_t)tid * DD;
    const float* qb   = qn + (size_t)b * LQ * DD;   // wave-uniform base

    float acc[LQ];
#pragma unroll
    for (int i = 0; i < LQ; ++i) acc[i] = 0.0f;
    float ssq = 0.0f;

#pragma unroll 1
    for (int c = 0; c < 4; ++c) {      // 4 chunks of 32 floats (one 128B line)
        float4 d4[8];
        const float4* p4 = reinterpret_cast<const float4*>(drow + c * 32);
#pragma unroll
        for (int i = 0; i < 8; ++i) d4[i] = p4[i];
        float dv[32];
#pragma unroll
        for (int i = 0; i < 8; ++i) {
            dv[4*i+0] = d4[i].x; dv[4*i+1] = d4[i].y;
            dv[4*i+2] = d4[i].z; dv[4*i+3] = d4[i].w;
        }
#pragma unroll
        for (int k = 0; k < 32; ++k) ssq += dv[k] * dv[k];
        const float* qc = qb + c * 32;
#pragma unroll
        for (int lq = 0; lq < LQ; ++lq) {
            const float* qp = qc + lq * DD;   // uniform across wave -> s_load
#pragma unroll
            for (int k = 0; k < 32; ++k) acc[lq] += qp[k] * dv[k];
        }
    }

    int mk = mask[(size_t)nb * LD + tid];
    float inv = 1.0f / fmaxf(sqrtf(ssq), EPSN);

    // per-lq masked score, wave-level max over this wave's 64 rows
    float red[LQ];
#pragma unroll
    for (int lq = 0; lq < LQ; ++lq) {
        float s = mk ? acc[lq] * inv : NEGV;
#pragma unroll
        for (int o = 32; o; o >>= 1) s = fmaxf(s, __shfl_xor(s, o));
        red[lq] = s;
    }

    // cross-wave max via LDS, then sum over lq
    __shared__ float wm[4][32];
    int lane = tid & 63, wv = tid >> 6;
    float sel = NEGV;
#pragma unroll
    for (int lq = 0; lq < LQ; ++lq)
        if ((lane & 31) == lq) sel = red[lq];
    if (lane < 32) wm[wv][lane] = sel;
    __syncthreads();
    if (tid < 32) {
        float v = fmaxf(fmaxf(wm[0][tid], wm[1][tid]),
                        fmaxf(wm[2][tid], wm[3][tid]));
#pragma unroll
        for (int o = 16; o; o >>= 1) v += __shfl_xor(v, o, 32);
        if (tid == 0) {
            int n = nb >> 7;
            scores[tensor * (Bq * Nn) + b * Nn + n] = v;
        }
    }
}

// ---------------- Kernel 3: log_softmax + KL ----------------
__global__ void loss_k(const float* __restrict__ scores, float* __restrict__ out) {
    int tid = threadIdx.x;   // 128 threads, one per b
    const float* s = scores + tid * Nn;            // student (cq)
    const float* t = scores + Bq * Nn + tid * Nn;  // teacher (orig)
    float sv[Nn], tv[Nn];
#pragma unroll
    for (int n = 0; n < Nn; ++n) { sv[n] = s[n]; tv[n] = t[n]; }
    float ms = sv[0], mt = tv[0];
#pragma unroll
    for (int n = 1; n < Nn; ++n) { ms = fmaxf(ms, sv[n]); mt = fmaxf(mt, tv[n]); }
    float es = 0.0f, et = 0.0f;
#pragma unroll
    for (int n = 0; n < Nn; ++n) { es += expf(sv[n] - ms); et += expf(tv[n] - mt); }
    float lses = ms + logf(es);
    float lset = mt + logf(et);
    double kl = 0.0;
#pragma unroll
    for (int n = 0; n < Nn; ++n) {
        float lt = tv[n] - lset;
        float ls = sv[n] - lses;
        kl += (double)expf(lt) * ((double)lt - (double)ls);
    }
#pragma unroll
    for (int o = 32; o; o >>= 1) kl += __shfl_xor(kl, o);
    __shared__ double part[2];
    if ((tid & 63) == 0) part[tid >> 6] = kl;
    __syncthreads();
    if (tid == 0) out[0] = (float)((part[0] + part[1]) / (double)Bq);
}

extern "C" void kernel_launch(void* const* d_in, const int* in_sizes, int n_in,
                              void* d_out, int out_size, void* d_ws, size_t ws_size,
                              hipStream_t stream) {
    const float* q     = (const float*)d_in[0];
    const float* dcq   = (const float*)d_in[1];
    const float* dorig = (const float*)d_in[2];
    const int*   mask  = (const int*)d_in[3];
    // labels (d_in[4]) unused by the reference loss path

    float* qn     = (float*)d_ws;                      // [B*LQ*DD] = 2MB
    float* scores = qn + (size_t)Bq * LQ * DD;         // [2][B][N] = 8KB

    qnorm_k<<<(Bq * LQ) / 4, 256, 0, stream>>>(q, qn);
    maxsim_k<<<2 * Nn * Bq, 256, 0, stream>>>(dcq, dorig, mask, qn, scores);
    loss_k<<<1, 128, 0, stream>>>(scores, (float*)d_out);
}